// Round 11
// baseline (358.749 us; speedup 1.0000x reference)
//
#include <hip/hip_runtime.h>
#include <stdint.h>

#define BATCH 2
#define SEQ   2048
#define DIM   1024
#define NH    16
#define DH    64

typedef short bf16x8 __attribute__((ext_vector_type(8)));
typedef float floatx4 __attribute__((ext_vector_type(4)));

__device__ __forceinline__ int swz(int r) { return (r ^ (r >> 2)) & 3; }

// Split two fp32 into packed bf16 hi-pair and lo-pair (truncation split)
__device__ __forceinline__ void split2(float x0, float x1, uint32_t& hi, uint32_t& lo) {
    uint32_t u0 = __float_as_uint(x0), u1 = __float_as_uint(x1);
    uint32_t m0 = u0 & 0xFFFF0000u;
    uint32_t m1 = u1 & 0xFFFF0000u;
    hi = (u0 >> 16) | m1;
    float l0 = x0 - __uint_as_float(m0);
    float l1 = x1 - __uint_as_float(m1);
    lo = (__float_as_uint(l0) >> 16) | (__float_as_uint(l1) & 0xFFFF0000u);
}

__device__ __forceinline__ uint32_t pack_bf16_rne(float x0, float x1) {
    uint32_t u0 = __float_as_uint(x0), u1 = __float_as_uint(x1);
    u0 += 0x7FFFu + ((u0 >> 16) & 1);
    u1 += 0x7FFFu + ((u1 >> 16) & 1);
    return (u0 >> 16) | (u1 & 0xFFFF0000u);
}

// ---------------- fused qv+k projection GEMM + register prefetch ------------
// R9/R10 geometry (768 blocks = 3/CU); K-loop restructured like R10's flash:
// split prefetched regs BEFORE barrier 1, pure ds_write between barriers,
// prefetch next k-tile's raw floats after barrier 2 (hidden under 48 MFMAs).
__global__ __launch_bounds__(256, 3)
void gemm_qvk(const float* __restrict__ Aqv, const float* __restrict__ Akp,
              const float* __restrict__ Wqv, const float* __restrict__ Wkp,
              uint32_t* __restrict__ qh, uint32_t* __restrict__ ql,
              uint32_t* __restrict__ vb,
              uint32_t* __restrict__ kh, uint32_t* __restrict__ kl)
{
    __shared__ uint32_t Ah[128 * 16], Al[128 * 16], Bh[128 * 16], Bl[128 * 16];

    const int t    = threadIdx.x;
    const int lane = t & 63;
    const int w    = t >> 6;
    const int wm   = w & 1, wn = w >> 1;
    const int quad = lane >> 4, l15 = lane & 15;
    const int bx   = blockIdx.x;
    const bool is_qv = (bx < 16);
    const float* Af = is_qv ? Aqv : Akp;
    const float* Bf = is_qv ? Wqv : Wkp;
    const int N    = is_qv ? 2048 : 1024;
    const int n0   = (is_qv ? bx : bx - 16) * 128;
    const int m0   = blockIdx.y * 128;

    const int ar  = t >> 1;
    const int ab0 = (t & 1) * 2;
    const int as  = swz(ar);
    const int bc  = (t & 31) * 4;
    const int bk  = (t >> 5) * 4;
    const int bb  = bk >> 3;
    const int bp  = (bk & 7) >> 1;

    floatx4 acc[4][4];
    #pragma unroll
    for (int i = 0; i < 4; i++)
        #pragma unroll
        for (int j = 0; j < 4; j++)
            #pragma unroll
            for (int e = 0; e < 4; e++) acc[i][j][e] = 0.0f;

    // ---- prefetch k0=0 raw floats ----
    float fA[16];
    float g4[4][4];
    {
        #pragma unroll
        for (int i = 0; i < 4; i++)
            *(float4*)&fA[i * 4] =
                *(const float4*)&Af[(size_t)(m0 + ar) * 1024 + ab0 * 8 + i * 4];
        #pragma unroll
        for (int j = 0; j < 4; j++)
            *(float4*)&g4[j][0] = *(const float4*)&Bf[(size_t)(bk + j) * N + n0 + bc];
    }

    for (int k0 = 0; k0 < 1024; k0 += 32) {
        // ---- split prefetched regs (register-only; overlaps others' compute) ----
        uint32_t hiA[8], loA[8];
        #pragma unroll
        for (int j = 0; j < 8; j++) split2(fA[2 * j], fA[2 * j + 1], hiA[j], loA[j]);
        uint32_t bh0[4], bl0[4], bh1[4], bl1[4];
        #pragma unroll
        for (int nn = 0; nn < 4; nn++) {
            split2(g4[0][nn], g4[1][nn], bh0[nn], bl0[nn]);
            split2(g4[2][nn], g4[3][nn], bh1[nn], bl1[nn]);
        }

        if (k0) __syncthreads();
        // ---- stage from registers (pure ds_write) ----
        {
            int i0 = ar * 16 + ((ab0 ^ as) * 4);
            int i1 = ar * 16 + (((ab0 + 1) ^ as) * 4);
            *(uint4*)&Ah[i0] = make_uint4(hiA[0], hiA[1], hiA[2], hiA[3]);
            *(uint4*)&Ah[i1] = make_uint4(hiA[4], hiA[5], hiA[6], hiA[7]);
            *(uint4*)&Al[i0] = make_uint4(loA[0], loA[1], loA[2], loA[3]);
            *(uint4*)&Al[i1] = make_uint4(loA[4], loA[5], loA[6], loA[7]);
        }
        #pragma unroll
        for (int nn = 0; nn < 4; nn++) {
            int n = bc + nn;
            int bi = n * 16 + ((bb ^ swz(n)) * 4) + bp;
            *(uint2*)&Bh[bi] = make_uint2(bh0[nn], bh1[nn]);
            *(uint2*)&Bl[bi] = make_uint2(bl0[nn], bl1[nn]);
        }
        __syncthreads();

        // ---- prefetch k0+32 (completes during MFMAs below) ----
        if (k0 + 32 < 1024) {
            #pragma unroll
            for (int i = 0; i < 4; i++)
                *(float4*)&fA[i * 4] =
                    *(const float4*)&Af[(size_t)(m0 + ar) * 1024 + (k0 + 32) + ab0 * 8 + i * 4];
            #pragma unroll
            for (int j = 0; j < 4; j++)
                *(float4*)&g4[j][0] =
                    *(const float4*)&Bf[(size_t)(k0 + 32 + bk + j) * N + n0 + bc];
        }

        // ---- fragments + swapped MFMA (lane l15 = C-row) ----
        bf16x8 vbh[4], vbl[4];
        #pragma unroll
        for (int fn = 0; fn < 4; fn++) {
            int br = wn * 64 + fn * 16 + l15;
            int bi = br * 16 + ((quad ^ swz(br)) * 4);
            vbh[fn] = *(const bf16x8*)&Bh[bi];
            vbl[fn] = *(const bf16x8*)&Bl[bi];
        }
        #pragma unroll
        for (int fm = 0; fm < 4; fm++) {
            int arow = wm * 64 + fm * 16 + l15;
            int ai = arow * 16 + ((quad ^ swz(arow)) * 4);
            bf16x8 vah = *(const bf16x8*)&Ah[ai];
            bf16x8 val = *(const bf16x8*)&Al[ai];
            #pragma unroll
            for (int fn = 0; fn < 4; fn++) {
                acc[fm][fn] = __builtin_amdgcn_mfma_f32_16x16x32_bf16(vbh[fn], vah, acc[fm][fn], 0, 0, 0);
                acc[fm][fn] = __builtin_amdgcn_mfma_f32_16x16x32_bf16(vbl[fn], vah, acc[fm][fn], 0, 0, 0);
                acc[fm][fn] = __builtin_amdgcn_mfma_f32_16x16x32_bf16(vbh[fn], val, acc[fm][fn], 0, 0, 0);
            }
        }
    }

    #pragma unroll
    for (int fm = 0; fm < 4; fm++) {
        int row = m0 + wm * 64 + fm * 16 + l15;
        #pragma unroll
        for (int fn = 0; fn < 4; fn++) {
            int colb = n0 + wn * 64 + fn * 16 + quad * 4;
            floatx4 a = acc[fm][fn];
            if (is_qv) {
                if (colb < 1024) {
                    uint32_t h0, l0, h1, l1;
                    split2(a[0], a[1], h0, l0);
                    split2(a[2], a[3], h1, l1);
                    size_t wi = (size_t)row * 512 + (colb >> 1);
                    *(uint2*)&qh[wi] = make_uint2(h0, h1);
                    *(uint2*)&ql[wi] = make_uint2(l0, l1);
                } else {
                    uint32_t w0 = pack_bf16_rne(a[0], a[1]);
                    uint32_t w1 = pack_bf16_rne(a[2], a[3]);
                    *(uint2*)&vb[(size_t)row * 512 + ((colb - 1024) >> 1)] = make_uint2(w0, w1);
                }
            } else {
                uint32_t h0, l0, h1, l1;
                split2(a[0], a[1], h0, l0);
                split2(a[2], a[3], h1, l1);
                size_t wi = (size_t)row * 512 + (colb >> 1);
                *(uint2*)&kh[wi] = make_uint2(h0, h1);
                *(uint2*)&kl[wi] = make_uint2(l0, l1);
            }
        }
    }
}

// ---------------- proj GEMM, 128x64 tile + register prefetch ----------------
__global__ __launch_bounds__(256, 3)
void gemm_proj(const uint32_t* __restrict__ Ahg, const uint32_t* __restrict__ Alg,
               const float* __restrict__ Bf, const float* __restrict__ bias,
               float* __restrict__ Cf)
{
    __shared__ uint32_t Ah[128 * 16], Al[128 * 16], Bh[64 * 16], Bl[64 * 16];

    const int t    = threadIdx.x;
    const int lane = t & 63;
    const int w    = t >> 6;
    const int wm   = w & 1, wn = w >> 1;
    const int quad = lane >> 4, l15 = lane & 15;
    const int m0 = blockIdx.y * 128, n0 = blockIdx.x * 64;
    const int N  = 1024;

    const int bc  = (t & 15) * 4;
    const int bk  = (t >> 4) * 2;
    const int bkw = bk >> 1;
    const int kb  = bkw >> 2, wo = bkw & 3;
    // A staging coords (2 tiles of 256 16B-chunks)
    const int arow0 = t >> 2, akb = t & 3;

    floatx4 acc[4][2];
    #pragma unroll
    for (int i = 0; i < 4; i++)
        #pragma unroll
        for (int j = 0; j < 2; j++)
            #pragma unroll
            for (int e = 0; e < 4; e++) acc[i][j][e] = 0.0f;

    // ---- prefetch k0=0 ----
    uint4 pa[2][2];           // [chunk][h/l]
    float pg[2][4];           // B rows k0+bk, k0+bk+1
    {
        #pragma unroll
        for (int i = 0; i < 2; i++) {
            int row = ((t + i * 256) >> 2);
            size_t src = (size_t)(m0 + row) * 512 + akb * 4;
            pa[i][0] = *(const uint4*)&Ahg[src];
            pa[i][1] = *(const uint4*)&Alg[src];
        }
        *(float4*)&pg[0][0] = *(const float4*)&Bf[(size_t)bk * N + n0 + bc];
        *(float4*)&pg[1][0] = *(const float4*)&Bf[(size_t)(bk + 1) * N + n0 + bc];
    }

    for (int k0 = 0; k0 < 1024; k0 += 32) {
        // ---- split prefetched B (register-only) ----
        uint32_t bh_[4], bl_[4];
        #pragma unroll
        for (int nn = 0; nn < 4; nn++) split2(pg[0][nn], pg[1][nn], bh_[nn], bl_[nn]);

        if (k0) __syncthreads();
        // ---- stage from registers ----
        #pragma unroll
        for (int i = 0; i < 2; i++) {
            int row = ((t + i * 256) >> 2);
            int dst = row * 16 + ((akb ^ swz(row)) * 4);
            *(uint4*)&Ah[dst] = pa[i][0];
            *(uint4*)&Al[dst] = pa[i][1];
        }
        #pragma unroll
        for (int nn = 0; nn < 4; nn++) {
            int n = bc + nn;
            int bi = n * 16 + ((kb ^ swz(n)) * 4) + wo;
            Bh[bi] = bh_[nn];
            Bl[bi] = bl_[nn];
        }
        __syncthreads();

        // ---- prefetch k0+32 ----
        if (k0 + 32 < 1024) {
            #pragma unroll
            for (int i = 0; i < 2; i++) {
                int row = ((t + i * 256) >> 2);
                size_t src = (size_t)(m0 + row) * 512 + ((k0 + 32) >> 1) + akb * 4;
                pa[i][0] = *(const uint4*)&Ahg[src];
                pa[i][1] = *(const uint4*)&Alg[src];
            }
            *(float4*)&pg[0][0] = *(const float4*)&Bf[(size_t)(k0 + 32 + bk) * N + n0 + bc];
            *(float4*)&pg[1][0] = *(const float4*)&Bf[(size_t)(k0 + 32 + bk + 1) * N + n0 + bc];
        }

        bf16x8 vbh[2], vbl[2];
        #pragma unroll
        for (int fn = 0; fn < 2; fn++) {
            int br = wn * 32 + fn * 16 + l15;
            int bi = br * 16 + ((quad ^ swz(br)) * 4);
            vbh[fn] = *(const bf16x8*)&Bh[bi];
            vbl[fn] = *(const bf16x8*)&Bl[bi];
        }
        #pragma unroll
        for (int fm = 0; fm < 4; fm++) {
            int arow = wm * 64 + fm * 16 + l15;
            int ai = arow * 16 + ((quad ^ swz(arow)) * 4);
            bf16x8 vah = *(const bf16x8*)&Ah[ai];
            bf16x8 val = *(const bf16x8*)&Al[ai];
            #pragma unroll
            for (int fn = 0; fn < 2; fn++) {
                acc[fm][fn] = __builtin_amdgcn_mfma_f32_16x16x32_bf16(vbh[fn], vah, acc[fm][fn], 0, 0, 0);
                acc[fm][fn] = __builtin_amdgcn_mfma_f32_16x16x32_bf16(vbl[fn], vah, acc[fm][fn], 0, 0, 0);
                acc[fm][fn] = __builtin_amdgcn_mfma_f32_16x16x32_bf16(vbh[fn], val, acc[fm][fn], 0, 0, 0);
            }
        }
    }

    #pragma unroll
    for (int fm = 0; fm < 4; fm++) {
        int row = m0 + wm * 64 + fm * 16 + l15;
        #pragma unroll
        for (int fn = 0; fn < 2; fn++) {
            int colb = n0 + wn * 32 + fn * 16 + quad * 4;
            floatx4 a = acc[fm][fn];
            float4 bb4 = *(const float4*)&bias[colb];
            float4 v;
            v.x = a[0] + bb4.x; v.y = a[1] + bb4.y;
            v.z = a[2] + bb4.z; v.w = a[3] + bb4.w;
            *(float4*)&Cf[(size_t)row * N + colb] = v;
        }
    }
}

// ---------------- MFMA flash attention (byte-identical to R10 winner) -------
#define FST 34
__global__ __launch_bounds__(256, 2)
void flash_attn(const uint32_t* __restrict__ qhg, const uint32_t* __restrict__ qlg,
                const uint32_t* __restrict__ khg, const uint32_t* __restrict__ klg,
                const uint32_t* __restrict__ vbg,
                uint32_t* __restrict__ xhg, uint32_t* __restrict__ xlg)
{
    __shared__ uint32_t Qh[128 * FST], Ql[128 * FST];
    __shared__ uint32_t Kh[64 * FST],  Kl[64 * FST];
    __shared__ uint32_t Vt[64 * FST];
    __shared__ uint32_t Pt[128 * FST];

    const int t    = threadIdx.x;
    const int lane = t & 63;
    const int w    = t >> 6;
    const int quad = lane >> 4, l15 = lane & 15;
    const int qb = blockIdx.x;
    const int h  = blockIdx.y;
    const int b  = blockIdx.z;
    const float scale = 0.125f;

    const size_t rowbase = (size_t)b * SEQ;

    {
        int row = t >> 1, c0 = (t & 1) * 16;
        size_t gw = (rowbase + qb * 128 + row) * 512 + h * 32 + c0;
        #pragma unroll
        for (int j = 0; j < 4; j++) {
            *(uint4*)&Qh[row * FST + c0 + j * 4] = *(const uint4*)&qhg[gw + j * 4];
            *(uint4*)&Ql[row * FST + c0 + j * 4] = *(const uint4*)&qlg[gw + j * 4];
        }
    }

    const int krow = t >> 2, kc0 = (t & 3) * 8;
    const int vkey0 = (t & 15) * 4, vd0 = (t >> 4) * 4;
    uint4 pkh0, pkh1, pkl0, pkl1;
    uint2 pv0, pv1, pv2, pv3;
    {
        size_t gw = (rowbase + krow) * 512 + h * 32 + kc0;
        pkh0 = *(const uint4*)&khg[gw];
        pkh1 = *(const uint4*)&khg[gw + 4];
        pkl0 = *(const uint4*)&klg[gw];
        pkl1 = *(const uint4*)&klg[gw + 4];
        size_t vw = (rowbase + vkey0) * 512 + h * 32 + (vd0 >> 1);
        pv0 = *(const uint2*)&vbg[vw];
        pv1 = *(const uint2*)&vbg[vw + 512];
        pv2 = *(const uint2*)&vbg[vw + 1024];
        pv3 = *(const uint2*)&vbg[vw + 1536];
    }

    float m_i[2] = {-INFINITY, -INFINITY};
    float l_i[2] = {0.0f, 0.0f};
    floatx4 acc_o[2][4];
    #pragma unroll
    for (int nf = 0; nf < 2; nf++)
        #pragma unroll
        for (int fm = 0; fm < 4; fm++)
            #pragma unroll
            for (int e = 0; e < 4; e++) acc_o[nf][fm][e] = 0.0f;

    for (int kt = 0; kt < SEQ / 64; kt++) {
        __syncthreads();
        *(uint4*)&Kh[krow * FST + kc0]     = pkh0;
        *(uint4*)&Kh[krow * FST + kc0 + 4] = pkh1;
        *(uint4*)&Kl[krow * FST + kc0]     = pkl0;
        *(uint4*)&Kl[krow * FST + kc0 + 4] = pkl1;
        {
            uint32_t lo, hi;
            lo = (pv0.x & 0xFFFFu) | (pv1.x << 16);
            hi = (pv2.x & 0xFFFFu) | (pv3.x << 16);
            *(uint2*)&Vt[(vd0 + 0) * FST + (vkey0 >> 1)] = make_uint2(lo, hi);
            lo = (pv0.x >> 16) | (pv1.x & 0xFFFF0000u);
            hi = (pv2.x >> 16) | (pv3.x & 0xFFFF0000u);
            *(uint2*)&Vt[(vd0 + 1) * FST + (vkey0 >> 1)] = make_uint2(lo, hi);
            lo = (pv0.y & 0xFFFFu) | (pv1.y << 16);
            hi = (pv2.y & 0xFFFFu) | (pv3.y << 16);
            *(uint2*)&Vt[(vd0 + 2) * FST + (vkey0 >> 1)] = make_uint2(lo, hi);
            lo = (pv0.y >> 16) | (pv1.y & 0xFFFF0000u);
            hi = (pv2.y >> 16) | (pv3.y & 0xFFFF0000u);
            *(uint2*)&Vt[(vd0 + 3) * FST + (vkey0 >> 1)] = make_uint2(lo, hi);
        }
        __syncthreads();

        if (kt + 1 < SEQ / 64) {
            size_t gw = (rowbase + (kt + 1) * 64 + krow) * 512 + h * 32 + kc0;
            pkh0 = *(const uint4*)&khg[gw];
            pkh1 = *(const uint4*)&khg[gw + 4];
            pkl0 = *(const uint4*)&klg[gw];
            pkl1 = *(const uint4*)&klg[gw + 4];
            size_t vw = (rowbase + (kt + 1) * 64 + vkey0) * 512 + h * 32 + (vd0 >> 1);
            pv0 = *(const uint2*)&vbg[vw];
            pv1 = *(const uint2*)&vbg[vw + 512];
            pv2 = *(const uint2*)&vbg[vw + 1024];
            pv3 = *(const uint2*)&vbg[vw + 1536];
        }

        floatx4 sacc[2][4];
        #pragma unroll
        for (int nf = 0; nf < 2; nf++)
            #pragma unroll
            for (int fm = 0; fm < 4; fm++)
                #pragma unroll
                for (int e = 0; e < 4; e++) sacc[nf][fm][e] = 0.0f;

        #pragma unroll
        for (int s = 0; s < 2; s++) {
            bf16x8 vqh[2], vql[2];
            #pragma unroll
            for (int nf = 0; nf < 2; nf++) {
                int qi = (w * 32 + nf * 16 + l15) * FST + s * 16 + quad * 4;
                vqh[nf] = *(const bf16x8*)&Qh[qi];
                vql[nf] = *(const bf16x8*)&Ql[qi];
            }
            #pragma unroll
            for (int fm = 0; fm < 4; fm++) {
                int ki = (fm * 16 + l15) * FST + s * 16 + quad * 4;
                bf16x8 vkh = *(const bf16x8*)&Kh[ki];
                bf16x8 vkl = *(const bf16x8*)&Kl[ki];
                #pragma unroll
                for (int nf = 0; nf < 2; nf++) {
                    sacc[nf][fm] = __builtin_amdgcn_mfma_f32_16x16x32_bf16(vkh, vqh[nf], sacc[nf][fm], 0, 0, 0);
                    sacc[nf][fm] = __builtin_amdgcn_mfma_f32_16x16x32_bf16(vkh, vql[nf], sacc[nf][fm], 0, 0, 0);
                    sacc[nf][fm] = __builtin_amdgcn_mfma_f32_16x16x32_bf16(vkl, vqh[nf], sacc[nf][fm], 0, 0, 0);
                }
            }
        }

        #pragma unroll
        for (int nf = 0; nf < 2; nf++) {
            float p[4][4];
            float mt = -INFINITY;
            #pragma unroll
            for (int fm = 0; fm < 4; fm++)
                #pragma unroll
                for (int r = 0; r < 4; r++) {
                    p[fm][r] = sacc[nf][fm][r] * scale;
                    mt = fmaxf(mt, p[fm][r]);
                }
            mt = fmaxf(mt, __shfl_xor(mt, 16));
            mt = fmaxf(mt, __shfl_xor(mt, 32));
            float m_new = fmaxf(m_i[nf], mt);
            float alpha = __expf(m_i[nf] - m_new);
            float rs = 0.0f;
            #pragma unroll
            for (int fm = 0; fm < 4; fm++)
                #pragma unroll
                for (int r = 0; r < 4; r++) {
                    p[fm][r] = __expf(p[fm][r] - m_new);
                    rs += p[fm][r];
                }
            rs += __shfl_xor(rs, 16);
            rs += __shfl_xor(rs, 32);
            l_i[nf] = l_i[nf] * alpha + rs;
            m_i[nf] = m_new;
            #pragma unroll
            for (int fm = 0; fm < 4; fm++)
                #pragma unroll
                for (int e = 0; e < 4; e++) acc_o[nf][fm][e] *= alpha;

            int qrow = w * 32 + nf * 16 + l15;
            #pragma unroll
            for (int fm = 0; fm < 4; fm++) {
                uint32_t u0 = pack_bf16_rne(p[fm][0], p[fm][1]);
                uint32_t u1 = pack_bf16_rne(p[fm][2], p[fm][3]);
                *(uint2*)&Pt[qrow * FST + fm * 8 + quad * 2] = make_uint2(u0, u1);
            }
        }

        #pragma unroll
        for (int s = 0; s < 2; s++) {
            bf16x8 pb[2];
            #pragma unroll
            for (int nf = 0; nf < 2; nf++)
                pb[nf] = *(const bf16x8*)&Pt[(w * 32 + nf * 16 + l15) * FST + s * 16 + quad * 4];
            #pragma unroll
            for (int fm = 0; fm < 4; fm++) {
                bf16x8 va = *(const bf16x8*)&Vt[(fm * 16 + l15) * FST + s * 16 + quad * 4];
                #pragma unroll
                for (int nf = 0; nf < 2; nf++)
                    acc_o[nf][fm] = __builtin_amdgcn_mfma_f32_16x16x32_bf16(va, pb[nf], acc_o[nf][fm], 0, 0, 0);
            }
        }
    }

    #pragma unroll
    for (int nf = 0; nf < 2; nf++) {
        float rl = 1.0f / l_i[nf];
        size_t row = rowbase + qb * 128 + w * 32 + nf * 16 + l15;
        #pragma unroll
        for (int fm = 0; fm < 4; fm++) {
            int d0 = fm * 16 + quad * 4;
            uint32_t h0, l0, h1, l1;
            split2(acc_o[nf][fm][0] * rl, acc_o[nf][fm][1] * rl, h0, l0);
            split2(acc_o[nf][fm][2] * rl, acc_o[nf][fm][3] * rl, h1, l1);
            size_t wi = row * 512 + ((h * 64 + d0) >> 1);
            *(uint2*)&xhg[wi] = make_uint2(h0, h1);
            *(uint2*)&xlg[wi] = make_uint2(l0, l1);
        }
    }
}

extern "C" void kernel_launch(void* const* d_in, const int* in_sizes, int n_in,
                              void* d_out, int out_size, void* d_ws, size_t ws_size,
                              hipStream_t stream)
{
    const float* input_qv = (const float*)d_in[0];
    const float* input_k  = (const float*)d_in[1];
    const float* W_qv     = (const float*)d_in[2];
    const float* W_k      = (const float*)d_in[3];
    const float* W_proj   = (const float*)d_in[4];
    const float* b_proj   = (const float*)d_in[5];
    float* out = (float*)d_out;

    const size_t RW = 4096 * 512;            // words per [4096][1024-bf16] buffer
    uint32_t* qh = (uint32_t*)d_ws;          // 5 RW = 41.9 MB total
    uint32_t* ql = qh + RW;
    uint32_t* vb = ql + RW;
    uint32_t* xh = vb + RW;
    uint32_t* xl = xh + RW;
    uint32_t* kh = (uint32_t*)d_out;         // split K parked in d_out (16.8 MB);
    uint32_t* kl = kh + RW;                  // proj GEMM rewrites out afterwards

    dim3 blk(256);
    // fused qv+k projections: 768 blocks = exactly 3/CU, register prefetch
    gemm_qvk<<<dim3(24, 32), blk, 0, stream>>>(
        input_qv, input_k, W_qv, W_k, qh, ql, vb, kh, kl);
    // flash attention (R10 winner, unchanged)
    flash_attn<<<dim3(SEQ / 128, NH, BATCH), blk, 0, stream>>>(
        qh, ql, kh, kl, vb, xh, xl);
    // output projection + bias: 128x64 tiles, register prefetch
    gemm_proj<<<dim3(16, 32), blk, 0, stream>>>(
        xh, xl, W_proj, b_proj, out);
}

// Round 12
// 319.528 us; speedup vs baseline: 1.1227x; 1.1227x over previous
//
#include <hip/hip_runtime.h>
#include <stdint.h>

#define BATCH 2
#define SEQ   2048
#define DIM   1024
#define NH    16
#define DH    64

typedef short bf16x8 __attribute__((ext_vector_type(8)));
typedef float floatx4 __attribute__((ext_vector_type(4)));

__device__ __forceinline__ int swz(int r) { return (r ^ (r >> 2)) & 3; }

// Split two fp32 into packed bf16 hi-pair and lo-pair (truncation split)
__device__ __forceinline__ void split2(float x0, float x1, uint32_t& hi, uint32_t& lo) {
    uint32_t u0 = __float_as_uint(x0), u1 = __float_as_uint(x1);
    uint32_t m0 = u0 & 0xFFFF0000u;
    uint32_t m1 = u1 & 0xFFFF0000u;
    hi = (u0 >> 16) | m1;
    float l0 = x0 - __uint_as_float(m0);
    float l1 = x1 - __uint_as_float(m1);
    lo = (__float_as_uint(l0) >> 16) | (__float_as_uint(l1) & 0xFFFF0000u);
}

__device__ __forceinline__ uint32_t pack_bf16_rne(float x0, float x1) {
    uint32_t u0 = __float_as_uint(x0), u1 = __float_as_uint(x1);
    u0 += 0x7FFFu + ((u0 >> 16) & 1);
    u1 += 0x7FFFu + ((u1 >> 16) & 1);
    return (u0 >> 16) | (u1 & 0xFFFF0000u);
}

__device__ __forceinline__ ushort bf16_rne1(float x) {
    uint32_t u = __float_as_uint(x);
    u += 0x7FFFu + ((u >> 16) & 1);
    return (ushort)(u >> 16);
}

// softmax scale folded into K: 0.125 * log2(e) -> flash uses exp2
#define KSCALE 0.18033688011112042f

// ---------------- fused qv+k projection GEMM (R10-proven core) --------------
// Epilogue deltas vs R10: (1) k-proj pre-scales by KSCALE before split;
// (2) qv writes V TRANSPOSED: vt[h][d][token] bf16 (so flash stages V as a
//     pure copy, no in-flash transpose VALU).
__global__ __launch_bounds__(256, 3)
void gemm_qvk(const float* __restrict__ Aqv, const float* __restrict__ Akp,
              const float* __restrict__ Wqv, const float* __restrict__ Wkp,
              uint32_t* __restrict__ qh, uint32_t* __restrict__ ql,
              ushort* __restrict__ vt,
              uint32_t* __restrict__ kh, uint32_t* __restrict__ kl)
{
    __shared__ uint32_t Ah[128 * 16], Al[128 * 16], Bh[128 * 16], Bl[128 * 16];

    const int t    = threadIdx.x;
    const int lane = t & 63;
    const int w    = t >> 6;
    const int wm   = w & 1, wn = w >> 1;
    const int quad = lane >> 4, l15 = lane & 15;
    const int bx   = blockIdx.x;
    const bool is_qv = (bx < 16);
    const float* Af = is_qv ? Aqv : Akp;
    const float* Bf = is_qv ? Wqv : Wkp;
    const int N    = is_qv ? 2048 : 1024;
    const int n0   = (is_qv ? bx : bx - 16) * 128;
    const int m0   = blockIdx.y * 128;

    const int ar  = t >> 1;
    const int ab0 = (t & 1) * 2;
    const int as  = swz(ar);
    const int bc  = (t & 31) * 4;
    const int bk  = (t >> 5) * 4;
    const int bb  = bk >> 3;
    const int bp  = (bk & 7) >> 1;

    floatx4 acc[4][4];
    #pragma unroll
    for (int i = 0; i < 4; i++)
        #pragma unroll
        for (int j = 0; j < 4; j++)
            #pragma unroll
            for (int e = 0; e < 4; e++) acc[i][j][e] = 0.0f;

    for (int k0 = 0; k0 < 1024; k0 += 32) {
        if (k0) __syncthreads();
        {
            float f[16];
            #pragma unroll
            for (int i = 0; i < 4; i++)
                *(float4*)&f[i * 4] =
                    *(const float4*)&Af[(size_t)(m0 + ar) * 1024 + k0 + ab0 * 8 + i * 4];
            uint32_t hi[8], lo[8];
            #pragma unroll
            for (int j = 0; j < 8; j++) split2(f[2 * j], f[2 * j + 1], hi[j], lo[j]);
            int i0 = ar * 16 + ((ab0 ^ as) * 4);
            int i1 = ar * 16 + (((ab0 + 1) ^ as) * 4);
            *(uint4*)&Ah[i0] = make_uint4(hi[0], hi[1], hi[2], hi[3]);
            *(uint4*)&Ah[i1] = make_uint4(hi[4], hi[5], hi[6], hi[7]);
            *(uint4*)&Al[i0] = make_uint4(lo[0], lo[1], lo[2], lo[3]);
            *(uint4*)&Al[i1] = make_uint4(lo[4], lo[5], lo[6], lo[7]);
        }
        {
            float4 g4[4];
            #pragma unroll
            for (int j = 0; j < 4; j++)
                g4[j] = *(const float4*)&Bf[(size_t)(k0 + bk + j) * N + n0 + bc];
            #pragma unroll
            for (int nn = 0; nn < 4; nn++) {
                int n = bc + nn;
                float e0 = ((const float*)&g4[0])[nn];
                float e1 = ((const float*)&g4[1])[nn];
                float e2 = ((const float*)&g4[2])[nn];
                float e3 = ((const float*)&g4[3])[nn];
                uint32_t h0, q0, h1, q1;
                split2(e0, e1, h0, q0);
                split2(e2, e3, h1, q1);
                int bi = n * 16 + ((bb ^ swz(n)) * 4) + bp;
                *(uint2*)&Bh[bi] = make_uint2(h0, h1);
                *(uint2*)&Bl[bi] = make_uint2(q0, q1);
            }
        }
        __syncthreads();

        bf16x8 vbh[4], vbl[4];
        #pragma unroll
        for (int fn = 0; fn < 4; fn++) {
            int br = wn * 64 + fn * 16 + l15;
            int bi = br * 16 + ((quad ^ swz(br)) * 4);
            vbh[fn] = *(const bf16x8*)&Bh[bi];
            vbl[fn] = *(const bf16x8*)&Bl[bi];
        }
        #pragma unroll
        for (int fm = 0; fm < 4; fm++) {
            int arow = wm * 64 + fm * 16 + l15;
            int ai = arow * 16 + ((quad ^ swz(arow)) * 4);
            bf16x8 vah = *(const bf16x8*)&Ah[ai];
            bf16x8 val = *(const bf16x8*)&Al[ai];
            #pragma unroll
            for (int fn = 0; fn < 4; fn++) {
                acc[fm][fn] = __builtin_amdgcn_mfma_f32_16x16x32_bf16(vbh[fn], vah, acc[fm][fn], 0, 0, 0);
                acc[fm][fn] = __builtin_amdgcn_mfma_f32_16x16x32_bf16(vbl[fn], vah, acc[fm][fn], 0, 0, 0);
                acc[fm][fn] = __builtin_amdgcn_mfma_f32_16x16x32_bf16(vbh[fn], val, acc[fm][fn], 0, 0, 0);
            }
        }
    }

    #pragma unroll
    for (int fm = 0; fm < 4; fm++) {
        int row = m0 + wm * 64 + fm * 16 + l15;
        #pragma unroll
        for (int fn = 0; fn < 4; fn++) {
            int colb = n0 + wn * 64 + fn * 16 + quad * 4;
            floatx4 a = acc[fm][fn];
            if (is_qv) {
                if (colb < 1024) {
                    uint32_t h0, l0, h1, l1;
                    split2(a[0], a[1], h0, l0);
                    split2(a[2], a[3], h1, l1);
                    size_t wi = (size_t)row * 512 + (colb >> 1);
                    *(uint2*)&qh[wi] = make_uint2(h0, h1);
                    *(uint2*)&ql[wi] = make_uint2(l0, l1);
                } else {
                    // V transposed: vt[h][d][token] bf16
                    int hh = (colb - 1024) >> 6;
                    int d0 = (colb - 1024) & 63;
                    #pragma unroll
                    for (int j = 0; j < 4; j++)
                        vt[(size_t)(hh * 64 + d0 + j) * 4096 + row] = bf16_rne1(a[j]);
                }
            } else {
                // K pre-scaled by KSCALE (softmax scale * log2e folded in)
                uint32_t h0, l0, h1, l1;
                split2(a[0] * KSCALE, a[1] * KSCALE, h0, l0);
                split2(a[2] * KSCALE, a[3] * KSCALE, h1, l1);
                size_t wi = (size_t)row * 512 + (colb >> 1);
                *(uint2*)&kh[wi] = make_uint2(h0, h1);
                *(uint2*)&kl[wi] = make_uint2(l0, l1);
            }
        }
    }
}

// ---------------- proj GEMM, 128x64 tile (R10-proven, unchanged) ------------
__global__ __launch_bounds__(256, 3)
void gemm_proj(const uint32_t* __restrict__ Ahg, const uint32_t* __restrict__ Alg,
               const float* __restrict__ Bf, const float* __restrict__ bias,
               float* __restrict__ Cf)
{
    __shared__ uint32_t Ah[128 * 16], Al[128 * 16], Bh[64 * 16], Bl[64 * 16];

    const int t    = threadIdx.x;
    const int lane = t & 63;
    const int w    = t >> 6;
    const int wm   = w & 1, wn = w >> 1;
    const int quad = lane >> 4, l15 = lane & 15;
    const int m0 = blockIdx.y * 128, n0 = blockIdx.x * 64;
    const int N  = 1024;

    const int bc  = (t & 15) * 4;
    const int bk  = (t >> 4) * 2;
    const int bkw = bk >> 1;
    const int kb  = bkw >> 2, wo = bkw & 3;

    floatx4 acc[4][2];
    #pragma unroll
    for (int i = 0; i < 4; i++)
        #pragma unroll
        for (int j = 0; j < 2; j++)
            #pragma unroll
            for (int e = 0; e < 4; e++) acc[i][j][e] = 0.0f;

    for (int k0 = 0; k0 < 1024; k0 += 32) {
        if (k0) __syncthreads();
        #pragma unroll
        for (int i = 0; i < 2; i++) {
            int idx = t + i * 256;
            int row = idx >> 2, kbl = idx & 3;
            size_t src = (size_t)(m0 + row) * 512 + (k0 >> 1) + kbl * 4;
            int dst = row * 16 + ((kbl ^ swz(row)) * 4);
            *(uint4*)&Ah[dst] = *(const uint4*)&Ahg[src];
            *(uint4*)&Al[dst] = *(const uint4*)&Alg[src];
        }
        {
            float4 g0 = *(const float4*)&Bf[(size_t)(k0 + bk) * N + n0 + bc];
            float4 g1 = *(const float4*)&Bf[(size_t)(k0 + bk + 1) * N + n0 + bc];
            const float* p0 = (const float*)&g0;
            const float* p1 = (const float*)&g1;
            #pragma unroll
            for (int nn = 0; nn < 4; nn++) {
                int n = bc + nn;
                uint32_t h, l;
                split2(p0[nn], p1[nn], h, l);
                int bi = n * 16 + ((kb ^ swz(n)) * 4) + wo;
                Bh[bi] = h;
                Bl[bi] = l;
            }
        }
        __syncthreads();

        bf16x8 vbh[2], vbl[2];
        #pragma unroll
        for (int fn = 0; fn < 2; fn++) {
            int br = wn * 32 + fn * 16 + l15;
            int bi = br * 16 + ((quad ^ swz(br)) * 4);
            vbh[fn] = *(const bf16x8*)&Bh[bi];
            vbl[fn] = *(const bf16x8*)&Bl[bi];
        }
        #pragma unroll
        for (int fm = 0; fm < 4; fm++) {
            int arow = wm * 64 + fm * 16 + l15;
            int ai = arow * 16 + ((quad ^ swz(arow)) * 4);
            bf16x8 vah = *(const bf16x8*)&Ah[ai];
            bf16x8 val = *(const bf16x8*)&Al[ai];
            #pragma unroll
            for (int fn = 0; fn < 2; fn++) {
                acc[fm][fn] = __builtin_amdgcn_mfma_f32_16x16x32_bf16(vbh[fn], vah, acc[fm][fn], 0, 0, 0);
                acc[fm][fn] = __builtin_amdgcn_mfma_f32_16x16x32_bf16(vbl[fn], vah, acc[fm][fn], 0, 0, 0);
                acc[fm][fn] = __builtin_amdgcn_mfma_f32_16x16x32_bf16(vbh[fn], val, acc[fm][fn], 0, 0, 0);
            }
        }
    }

    #pragma unroll
    for (int fm = 0; fm < 4; fm++) {
        int row = m0 + wm * 64 + fm * 16 + l15;
        #pragma unroll
        for (int fn = 0; fn < 2; fn++) {
            int colb = n0 + wn * 32 + fn * 16 + quad * 4;
            floatx4 a = acc[fm][fn];
            float4 bb4 = *(const float4*)&bias[colb];
            float4 v;
            v.x = a[0] + bb4.x; v.y = a[1] + bb4.y;
            v.z = a[2] + bb4.z; v.w = a[3] + bb4.w;
            *(float4*)&Cf[(size_t)row * N + colb] = v;
        }
    }
}

// ---------------- MFMA flash attention, Br=128, Bc=64 -----------------------
// R10 winner + (1) V staged as pure prefetch+copy from pre-transposed vt;
// (2) K pre-scaled in GEMM -> no scale mul; exp2 softmax domain.
#define FST 34
__global__ __launch_bounds__(256, 2)
void flash_attn(const uint32_t* __restrict__ qhg, const uint32_t* __restrict__ qlg,
                const uint32_t* __restrict__ khg, const uint32_t* __restrict__ klg,
                const uint32_t* __restrict__ vtg,
                uint32_t* __restrict__ xhg, uint32_t* __restrict__ xlg)
{
    __shared__ uint32_t Qh[128 * FST], Ql[128 * FST];
    __shared__ uint32_t Kh[64 * FST],  Kl[64 * FST];
    __shared__ uint32_t Vt[64 * FST];
    __shared__ uint32_t Pt[128 * FST];

    const int t    = threadIdx.x;
    const int lane = t & 63;
    const int w    = t >> 6;
    const int quad = lane >> 4, l15 = lane & 15;
    const int qb = blockIdx.x;
    const int h  = blockIdx.y;
    const int b  = blockIdx.z;

    const size_t rowbase = (size_t)b * SEQ;

    // ---- stage Q tile once ----
    {
        int row = t >> 1, c0 = (t & 1) * 16;
        size_t gw = (rowbase + qb * 128 + row) * 512 + h * 32 + c0;
        #pragma unroll
        for (int j = 0; j < 4; j++) {
            *(uint4*)&Qh[row * FST + c0 + j * 4] = *(const uint4*)&qhg[gw + j * 4];
            *(uint4*)&Ql[row * FST + c0 + j * 4] = *(const uint4*)&qlg[gw + j * 4];
        }
    }

    // ---- prefetch coords + tile kt=0 ----
    const int krow = t >> 2, kc0 = (t & 3) * 8;          // K: row, word base
    const int vd = t >> 2, vc = t & 3;                   // V^T: d row, key chunk
    const size_t vrow = (size_t)(h * 64 + vd) * 2048 + (rowbase >> 1);
    uint4 pkh0, pkh1, pkl0, pkl1;
    uint4 pv0, pv1;
    {
        size_t gw = (rowbase + krow) * 512 + h * 32 + kc0;
        pkh0 = *(const uint4*)&khg[gw];
        pkh1 = *(const uint4*)&khg[gw + 4];
        pkl0 = *(const uint4*)&klg[gw];
        pkl1 = *(const uint4*)&klg[gw + 4];
        size_t vw = vrow + vc * 8;
        pv0 = *(const uint4*)&vtg[vw];
        pv1 = *(const uint4*)&vtg[vw + 4];
    }

    float m_i[2] = {-INFINITY, -INFINITY};
    float l_i[2] = {0.0f, 0.0f};
    floatx4 acc_o[2][4];
    #pragma unroll
    for (int nf = 0; nf < 2; nf++)
        #pragma unroll
        for (int fm = 0; fm < 4; fm++)
            #pragma unroll
            for (int e = 0; e < 4; e++) acc_o[nf][fm][e] = 0.0f;

    for (int kt = 0; kt < SEQ / 64; kt++) {
        __syncthreads();
        // ---- stage K from registers ----
        *(uint4*)&Kh[krow * FST + kc0]     = pkh0;
        *(uint4*)&Kh[krow * FST + kc0 + 4] = pkh1;
        *(uint4*)&Kl[krow * FST + kc0]     = pkl0;
        *(uint4*)&Kl[krow * FST + kc0 + 4] = pkl1;
        // ---- stage V^T from registers (pure copy; uint2 stores for alignment) ----
        {
            int vb0 = vd * FST + vc * 8;
            *(uint2*)&Vt[vb0]     = make_uint2(pv0.x, pv0.y);
            *(uint2*)&Vt[vb0 + 2] = make_uint2(pv0.z, pv0.w);
            *(uint2*)&Vt[vb0 + 4] = make_uint2(pv1.x, pv1.y);
            *(uint2*)&Vt[vb0 + 6] = make_uint2(pv1.z, pv1.w);
        }
        __syncthreads();

        // ---- prefetch tile kt+1 (completes during compute) ----
        if (kt + 1 < SEQ / 64) {
            size_t gw = (rowbase + (kt + 1) * 64 + krow) * 512 + h * 32 + kc0;
            pkh0 = *(const uint4*)&khg[gw];
            pkh1 = *(const uint4*)&khg[gw + 4];
            pkl0 = *(const uint4*)&klg[gw];
            pkl1 = *(const uint4*)&klg[gw + 4];
            size_t vw = vrow + (kt + 1) * 32 + vc * 8;
            pv0 = *(const uint4*)&vtg[vw];
            pv1 = *(const uint4*)&vtg[vw + 4];
        }

        // ---- S^T = K·Q^T (bf16x3); K carries scale*log2e already ----
        floatx4 sacc[2][4];
        #pragma unroll
        for (int nf = 0; nf < 2; nf++)
            #pragma unroll
            for (int fm = 0; fm < 4; fm++)
                #pragma unroll
                for (int e = 0; e < 4; e++) sacc[nf][fm][e] = 0.0f;

        #pragma unroll
        for (int s = 0; s < 2; s++) {
            bf16x8 vqh[2], vql[2];
            #pragma unroll
            for (int nf = 0; nf < 2; nf++) {
                int qi = (w * 32 + nf * 16 + l15) * FST + s * 16 + quad * 4;
                vqh[nf] = *(const bf16x8*)&Qh[qi];
                vql[nf] = *(const bf16x8*)&Ql[qi];
            }
            #pragma unroll
            for (int fm = 0; fm < 4; fm++) {
                int ki = (fm * 16 + l15) * FST + s * 16 + quad * 4;
                bf16x8 vkh = *(const bf16x8*)&Kh[ki];
                bf16x8 vkl = *(const bf16x8*)&Kl[ki];
                #pragma unroll
                for (int nf = 0; nf < 2; nf++) {
                    sacc[nf][fm] = __builtin_amdgcn_mfma_f32_16x16x32_bf16(vkh, vqh[nf], sacc[nf][fm], 0, 0, 0);
                    sacc[nf][fm] = __builtin_amdgcn_mfma_f32_16x16x32_bf16(vkh, vql[nf], sacc[nf][fm], 0, 0, 0);
                    sacc[nf][fm] = __builtin_amdgcn_mfma_f32_16x16x32_bf16(vkl, vqh[nf], sacc[nf][fm], 0, 0, 0);
                }
            }
        }

        // ---- online softmax (base-2 domain) ----
        #pragma unroll
        for (int nf = 0; nf < 2; nf++) {
            float p[4][4];
            float mt = -INFINITY;
            #pragma unroll
            for (int fm = 0; fm < 4; fm++)
                #pragma unroll
                for (int r = 0; r < 4; r++) {
                    p[fm][r] = sacc[nf][fm][r];
                    mt = fmaxf(mt, p[fm][r]);
                }
            mt = fmaxf(mt, __shfl_xor(mt, 16));
            mt = fmaxf(mt, __shfl_xor(mt, 32));
            float m_new = fmaxf(m_i[nf], mt);
            float alpha = exp2f(m_i[nf] - m_new);
            float rs = 0.0f;
            #pragma unroll
            for (int fm = 0; fm < 4; fm++)
                #pragma unroll
                for (int r = 0; r < 4; r++) {
                    p[fm][r] = exp2f(p[fm][r] - m_new);
                    rs += p[fm][r];
                }
            rs += __shfl_xor(rs, 16);
            rs += __shfl_xor(rs, 32);
            l_i[nf] = l_i[nf] * alpha + rs;
            m_i[nf] = m_new;
            #pragma unroll
            for (int fm = 0; fm < 4; fm++)
                #pragma unroll
                for (int e = 0; e < 4; e++) acc_o[nf][fm][e] *= alpha;

            int qrow = w * 32 + nf * 16 + l15;
            #pragma unroll
            for (int fm = 0; fm < 4; fm++) {
                uint32_t u0 = pack_bf16_rne(p[fm][0], p[fm][1]);
                uint32_t u1 = pack_bf16_rne(p[fm][2], p[fm][3]);
                *(uint2*)&Pt[qrow * FST + fm * 8 + quad * 2] = make_uint2(u0, u1);
            }
        }

        // ---- O^T += Vt · P^T ----
        #pragma unroll
        for (int s = 0; s < 2; s++) {
            bf16x8 pb[2];
            #pragma unroll
            for (int nf = 0; nf < 2; nf++)
                pb[nf] = *(const bf16x8*)&Pt[(w * 32 + nf * 16 + l15) * FST + s * 16 + quad * 4];
            #pragma unroll
            for (int fm = 0; fm < 4; fm++) {
                bf16x8 va = *(const bf16x8*)&Vt[(fm * 16 + l15) * FST + s * 16 + quad * 4];
                #pragma unroll
                for (int nf = 0; nf < 2; nf++)
                    acc_o[nf][fm] = __builtin_amdgcn_mfma_f32_16x16x32_bf16(va, pb[nf], acc_o[nf][fm], 0, 0, 0);
            }
        }
    }

    // ---- epilogue: write x pre-split bf16 ----
    #pragma unroll
    for (int nf = 0; nf < 2; nf++) {
        float rl = 1.0f / l_i[nf];
        size_t row = rowbase + qb * 128 + w * 32 + nf * 16 + l15;
        #pragma unroll
        for (int fm = 0; fm < 4; fm++) {
            int d0 = fm * 16 + quad * 4;
            uint32_t h0, l0, h1, l1;
            split2(acc_o[nf][fm][0] * rl, acc_o[nf][fm][1] * rl, h0, l0);
            split2(acc_o[nf][fm][2] * rl, acc_o[nf][fm][3] * rl, h1, l1);
            size_t wi = row * 512 + ((h * 64 + d0) >> 1);
            *(uint2*)&xhg[wi] = make_uint2(h0, h1);
            *(uint2*)&xlg[wi] = make_uint2(l0, l1);
        }
    }
}

extern "C" void kernel_launch(void* const* d_in, const int* in_sizes, int n_in,
                              void* d_out, int out_size, void* d_ws, size_t ws_size,
                              hipStream_t stream)
{
    const float* input_qv = (const float*)d_in[0];
    const float* input_k  = (const float*)d_in[1];
    const float* W_qv     = (const float*)d_in[2];
    const float* W_k      = (const float*)d_in[3];
    const float* W_proj   = (const float*)d_in[4];
    const float* b_proj   = (const float*)d_in[5];
    float* out = (float*)d_out;

    const size_t RW = 4096 * 512;            // words per [4096][1024-bf16] buffer
    uint32_t* qh = (uint32_t*)d_ws;          // 5 RW = 41.9 MB total
    uint32_t* ql = qh + RW;
    uint32_t* vt = ql + RW;                  // V^T [16 h][64 d][4096 tok] bf16 = 1 RW
    uint32_t* xh = vt + RW;
    uint32_t* xl = xh + RW;
    uint32_t* kh = (uint32_t*)d_out;         // split K parked in d_out (16.8 MB);
    uint32_t* kl = kh + RW;                  // proj GEMM rewrites out afterwards

    dim3 blk(256);
    // fused qv+k projections: 768 blocks = exactly 3/CU (R10-proven core)
    gemm_qvk<<<dim3(24, 32), blk, 0, stream>>>(
        input_qv, input_k, W_qv, W_k, qh, ql, (ushort*)vt, kh, kl);
    // flash attention (K/V register prefetch; V pre-transposed; exp2 softmax)
    flash_attn<<<dim3(SEQ / 128, NH, BATCH), blk, 0, stream>>>(
        qh, ql, kh, kl, vt, xh, xl);
    // output projection + bias (R10-proven, unchanged)
    gemm_proj<<<dim3(16, 32), blk, 0, stream>>>(
        xh, xl, W_proj, b_proj, out);
}

// Round 13
// 309.473 us; speedup vs baseline: 1.1592x; 1.0325x over previous
//
#include <hip/hip_runtime.h>
#include <stdint.h>

#define BATCH 2
#define SEQ   2048
#define DIM   1024
#define NH    16
#define DH    64

typedef short bf16x8 __attribute__((ext_vector_type(8)));
typedef float floatx4 __attribute__((ext_vector_type(4)));

__device__ __forceinline__ int swz(int r) { return (r ^ (r >> 2)) & 3; }

// fast 2^x: raw v_exp_f32
#if __has_builtin(__builtin_amdgcn_exp2f)
#define EXP2(x) __builtin_amdgcn_exp2f(x)
#else
#define EXP2(x) __expf((x) * 0.6931471805599453f)
#endif

// Split two fp32 into packed bf16 hi-pair and lo-pair (truncation split)
__device__ __forceinline__ void split2(float x0, float x1, uint32_t& hi, uint32_t& lo) {
    uint32_t u0 = __float_as_uint(x0), u1 = __float_as_uint(x1);
    uint32_t m0 = u0 & 0xFFFF0000u;
    uint32_t m1 = u1 & 0xFFFF0000u;
    hi = (u0 >> 16) | m1;
    float l0 = x0 - __uint_as_float(m0);
    float l1 = x1 - __uint_as_float(m1);
    lo = (__float_as_uint(l0) >> 16) | (__float_as_uint(l1) & 0xFFFF0000u);
}

__device__ __forceinline__ uint32_t pack_bf16_rne(float x0, float x1) {
    uint32_t u0 = __float_as_uint(x0), u1 = __float_as_uint(x1);
    u0 += 0x7FFFu + ((u0 >> 16) & 1);
    u1 += 0x7FFFu + ((u1 >> 16) & 1);
    return (u0 >> 16) | (u1 & 0xFFFF0000u);
}

__device__ __forceinline__ ushort bf16_rne1(float x) {
    uint32_t u = __float_as_uint(x);
    u += 0x7FFFu + ((u >> 16) & 1);
    return (ushort)(u >> 16);
}

// softmax scale folded into K: 0.125 * log2(e) -> flash uses exp2
#define KSCALE 0.18033688011112042f

// ---------------- fused qv+k projection GEMM (R12-proven, unchanged) --------
__global__ __launch_bounds__(256, 3)
void gemm_qvk(const float* __restrict__ Aqv, const float* __restrict__ Akp,
              const float* __restrict__ Wqv, const float* __restrict__ Wkp,
              uint32_t* __restrict__ qh, uint32_t* __restrict__ ql,
              ushort* __restrict__ vt,
              uint32_t* __restrict__ kh, uint32_t* __restrict__ kl)
{
    __shared__ uint32_t Ah[128 * 16], Al[128 * 16], Bh[128 * 16], Bl[128 * 16];

    const int t    = threadIdx.x;
    const int lane = t & 63;
    const int w    = t >> 6;
    const int wm   = w & 1, wn = w >> 1;
    const int quad = lane >> 4, l15 = lane & 15;
    const int bx   = blockIdx.x;
    const bool is_qv = (bx < 16);
    const float* Af = is_qv ? Aqv : Akp;
    const float* Bf = is_qv ? Wqv : Wkp;
    const int N    = is_qv ? 2048 : 1024;
    const int n0   = (is_qv ? bx : bx - 16) * 128;
    const int m0   = blockIdx.y * 128;

    const int ar  = t >> 1;
    const int ab0 = (t & 1) * 2;
    const int as  = swz(ar);
    const int bc  = (t & 31) * 4;
    const int bk  = (t >> 5) * 4;
    const int bb  = bk >> 3;
    const int bp  = (bk & 7) >> 1;

    floatx4 acc[4][4];
    #pragma unroll
    for (int i = 0; i < 4; i++)
        #pragma unroll
        for (int j = 0; j < 4; j++)
            #pragma unroll
            for (int e = 0; e < 4; e++) acc[i][j][e] = 0.0f;

    for (int k0 = 0; k0 < 1024; k0 += 32) {
        if (k0) __syncthreads();
        {
            float f[16];
            #pragma unroll
            for (int i = 0; i < 4; i++)
                *(float4*)&f[i * 4] =
                    *(const float4*)&Af[(size_t)(m0 + ar) * 1024 + k0 + ab0 * 8 + i * 4];
            uint32_t hi[8], lo[8];
            #pragma unroll
            for (int j = 0; j < 8; j++) split2(f[2 * j], f[2 * j + 1], hi[j], lo[j]);
            int i0 = ar * 16 + ((ab0 ^ as) * 4);
            int i1 = ar * 16 + (((ab0 + 1) ^ as) * 4);
            *(uint4*)&Ah[i0] = make_uint4(hi[0], hi[1], hi[2], hi[3]);
            *(uint4*)&Ah[i1] = make_uint4(hi[4], hi[5], hi[6], hi[7]);
            *(uint4*)&Al[i0] = make_uint4(lo[0], lo[1], lo[2], lo[3]);
            *(uint4*)&Al[i1] = make_uint4(lo[4], lo[5], lo[6], lo[7]);
        }
        {
            float4 g4[4];
            #pragma unroll
            for (int j = 0; j < 4; j++)
                g4[j] = *(const float4*)&Bf[(size_t)(k0 + bk + j) * N + n0 + bc];
            #pragma unroll
            for (int nn = 0; nn < 4; nn++) {
                int n = bc + nn;
                float e0 = ((const float*)&g4[0])[nn];
                float e1 = ((const float*)&g4[1])[nn];
                float e2 = ((const float*)&g4[2])[nn];
                float e3 = ((const float*)&g4[3])[nn];
                uint32_t h0, q0, h1, q1;
                split2(e0, e1, h0, q0);
                split2(e2, e3, h1, q1);
                int bi = n * 16 + ((bb ^ swz(n)) * 4) + bp;
                *(uint2*)&Bh[bi] = make_uint2(h0, h1);
                *(uint2*)&Bl[bi] = make_uint2(q0, q1);
            }
        }
        __syncthreads();

        bf16x8 vbh[4], vbl[4];
        #pragma unroll
        for (int fn = 0; fn < 4; fn++) {
            int br = wn * 64 + fn * 16 + l15;
            int bi = br * 16 + ((quad ^ swz(br)) * 4);
            vbh[fn] = *(const bf16x8*)&Bh[bi];
            vbl[fn] = *(const bf16x8*)&Bl[bi];
        }
        #pragma unroll
        for (int fm = 0; fm < 4; fm++) {
            int arow = wm * 64 + fm * 16 + l15;
            int ai = arow * 16 + ((quad ^ swz(arow)) * 4);
            bf16x8 vah = *(const bf16x8*)&Ah[ai];
            bf16x8 val = *(const bf16x8*)&Al[ai];
            #pragma unroll
            for (int fn = 0; fn < 4; fn++) {
                acc[fm][fn] = __builtin_amdgcn_mfma_f32_16x16x32_bf16(vbh[fn], vah, acc[fm][fn], 0, 0, 0);
                acc[fm][fn] = __builtin_amdgcn_mfma_f32_16x16x32_bf16(vbl[fn], vah, acc[fm][fn], 0, 0, 0);
                acc[fm][fn] = __builtin_amdgcn_mfma_f32_16x16x32_bf16(vbh[fn], val, acc[fm][fn], 0, 0, 0);
            }
        }
    }

    #pragma unroll
    for (int fm = 0; fm < 4; fm++) {
        int row = m0 + wm * 64 + fm * 16 + l15;
        #pragma unroll
        for (int fn = 0; fn < 4; fn++) {
            int colb = n0 + wn * 64 + fn * 16 + quad * 4;
            floatx4 a = acc[fm][fn];
            if (is_qv) {
                if (colb < 1024) {
                    uint32_t h0, l0, h1, l1;
                    split2(a[0], a[1], h0, l0);
                    split2(a[2], a[3], h1, l1);
                    size_t wi = (size_t)row * 512 + (colb >> 1);
                    *(uint2*)&qh[wi] = make_uint2(h0, h1);
                    *(uint2*)&ql[wi] = make_uint2(l0, l1);
                } else {
                    // V transposed: vt[h][d][token] bf16
                    int hh = (colb - 1024) >> 6;
                    int d0 = (colb - 1024) & 63;
                    #pragma unroll
                    for (int j = 0; j < 4; j++)
                        vt[(size_t)(hh * 64 + d0 + j) * 4096 + row] = bf16_rne1(a[j]);
                }
            } else {
                // K pre-scaled by KSCALE (softmax scale * log2e folded in)
                uint32_t h0, l0, h1, l1;
                split2(a[0] * KSCALE, a[1] * KSCALE, h0, l0);
                split2(a[2] * KSCALE, a[3] * KSCALE, h1, l1);
                size_t wi = (size_t)row * 512 + (colb >> 1);
                *(uint2*)&kh[wi] = make_uint2(h0, h1);
                *(uint2*)&kl[wi] = make_uint2(l0, l1);
            }
        }
    }
}

// ---------------- proj GEMM, 128x64 tile (R10-proven, unchanged) ------------
__global__ __launch_bounds__(256, 3)
void gemm_proj(const uint32_t* __restrict__ Ahg, const uint32_t* __restrict__ Alg,
               const float* __restrict__ Bf, const float* __restrict__ bias,
               float* __restrict__ Cf)
{
    __shared__ uint32_t Ah[128 * 16], Al[128 * 16], Bh[64 * 16], Bl[64 * 16];

    const int t    = threadIdx.x;
    const int lane = t & 63;
    const int w    = t >> 6;
    const int wm   = w & 1, wn = w >> 1;
    const int quad = lane >> 4, l15 = lane & 15;
    const int m0 = blockIdx.y * 128, n0 = blockIdx.x * 64;
    const int N  = 1024;

    const int bc  = (t & 15) * 4;
    const int bk  = (t >> 4) * 2;
    const int bkw = bk >> 1;
    const int kb  = bkw >> 2, wo = bkw & 3;

    floatx4 acc[4][2];
    #pragma unroll
    for (int i = 0; i < 4; i++)
        #pragma unroll
        for (int j = 0; j < 2; j++)
            #pragma unroll
            for (int e = 0; e < 4; e++) acc[i][j][e] = 0.0f;

    for (int k0 = 0; k0 < 1024; k0 += 32) {
        if (k0) __syncthreads();
        #pragma unroll
        for (int i = 0; i < 2; i++) {
            int idx = t + i * 256;
            int row = idx >> 2, kbl = idx & 3;
            size_t src = (size_t)(m0 + row) * 512 + (k0 >> 1) + kbl * 4;
            int dst = row * 16 + ((kbl ^ swz(row)) * 4);
            *(uint4*)&Ah[dst] = *(const uint4*)&Ahg[src];
            *(uint4*)&Al[dst] = *(const uint4*)&Alg[src];
        }
        {
            float4 g0 = *(const float4*)&Bf[(size_t)(k0 + bk) * N + n0 + bc];
            float4 g1 = *(const float4*)&Bf[(size_t)(k0 + bk + 1) * N + n0 + bc];
            const float* p0 = (const float*)&g0;
            const float* p1 = (const float*)&g1;
            #pragma unroll
            for (int nn = 0; nn < 4; nn++) {
                int n = bc + nn;
                uint32_t h, l;
                split2(p0[nn], p1[nn], h, l);
                int bi = n * 16 + ((kb ^ swz(n)) * 4) + wo;
                Bh[bi] = h;
                Bl[bi] = l;
            }
        }
        __syncthreads();

        bf16x8 vbh[2], vbl[2];
        #pragma unroll
        for (int fn = 0; fn < 2; fn++) {
            int br = wn * 32 + fn * 16 + l15;
            int bi = br * 16 + ((quad ^ swz(br)) * 4);
            vbh[fn] = *(const bf16x8*)&Bh[bi];
            vbl[fn] = *(const bf16x8*)&Bl[bi];
        }
        #pragma unroll
        for (int fm = 0; fm < 4; fm++) {
            int arow = wm * 64 + fm * 16 + l15;
            int ai = arow * 16 + ((quad ^ swz(arow)) * 4);
            bf16x8 vah = *(const bf16x8*)&Ah[ai];
            bf16x8 val = *(const bf16x8*)&Al[ai];
            #pragma unroll
            for (int fn = 0; fn < 2; fn++) {
                acc[fm][fn] = __builtin_amdgcn_mfma_f32_16x16x32_bf16(vbh[fn], vah, acc[fm][fn], 0, 0, 0);
                acc[fm][fn] = __builtin_amdgcn_mfma_f32_16x16x32_bf16(vbl[fn], vah, acc[fm][fn], 0, 0, 0);
                acc[fm][fn] = __builtin_amdgcn_mfma_f32_16x16x32_bf16(vbh[fn], val, acc[fm][fn], 0, 0, 0);
            }
        }
    }

    #pragma unroll
    for (int fm = 0; fm < 4; fm++) {
        int row = m0 + wm * 64 + fm * 16 + l15;
        #pragma unroll
        for (int fn = 0; fn < 2; fn++) {
            int colb = n0 + wn * 32 + fn * 16 + quad * 4;
            floatx4 a = acc[fm][fn];
            float4 bb4 = *(const float4*)&bias[colb];
            float4 v;
            v.x = a[0] + bb4.x; v.y = a[1] + bb4.y;
            v.z = a[2] + bb4.z; v.w = a[3] + bb4.w;
            *(float4*)&Cf[(size_t)row * N + colb] = v;
        }
    }
}

// ---------------- MFMA flash attention (R12 + raw v_exp_f32) ----------------
#define FST 34
__global__ __launch_bounds__(256, 2)
void flash_attn(const uint32_t* __restrict__ qhg, const uint32_t* __restrict__ qlg,
                const uint32_t* __restrict__ khg, const uint32_t* __restrict__ klg,
                const uint32_t* __restrict__ vtg,
                uint32_t* __restrict__ xhg, uint32_t* __restrict__ xlg)
{
    __shared__ uint32_t Qh[128 * FST], Ql[128 * FST];
    __shared__ uint32_t Kh[64 * FST],  Kl[64 * FST];
    __shared__ uint32_t Vt[64 * FST];
    __shared__ uint32_t Pt[128 * FST];

    const int t    = threadIdx.x;
    const int lane = t & 63;
    const int w    = t >> 6;
    const int quad = lane >> 4, l15 = lane & 15;
    const int qb = blockIdx.x;
    const int h  = blockIdx.y;
    const int b  = blockIdx.z;

    const size_t rowbase = (size_t)b * SEQ;

    // ---- stage Q tile once ----
    {
        int row = t >> 1, c0 = (t & 1) * 16;
        size_t gw = (rowbase + qb * 128 + row) * 512 + h * 32 + c0;
        #pragma unroll
        for (int j = 0; j < 4; j++) {
            *(uint4*)&Qh[row * FST + c0 + j * 4] = *(const uint4*)&qhg[gw + j * 4];
            *(uint4*)&Ql[row * FST + c0 + j * 4] = *(const uint4*)&qlg[gw + j * 4];
        }
    }

    // ---- prefetch coords + tile kt=0 ----
    const int krow = t >> 2, kc0 = (t & 3) * 8;
    const int vd = t >> 2, vc = t & 3;
    const size_t vrow = (size_t)(h * 64 + vd) * 2048 + (rowbase >> 1);
    uint4 pkh0, pkh1, pkl0, pkl1;
    uint4 pv0, pv1;
    {
        size_t gw = (rowbase + krow) * 512 + h * 32 + kc0;
        pkh0 = *(const uint4*)&khg[gw];
        pkh1 = *(const uint4*)&khg[gw + 4];
        pkl0 = *(const uint4*)&klg[gw];
        pkl1 = *(const uint4*)&klg[gw + 4];
        size_t vw = vrow + vc * 8;
        pv0 = *(const uint4*)&vtg[vw];
        pv1 = *(const uint4*)&vtg[vw + 4];
    }

    float m_i[2] = {-INFINITY, -INFINITY};
    float l_i[2] = {0.0f, 0.0f};
    floatx4 acc_o[2][4];
    #pragma unroll
    for (int nf = 0; nf < 2; nf++)
        #pragma unroll
        for (int fm = 0; fm < 4; fm++)
            #pragma unroll
            for (int e = 0; e < 4; e++) acc_o[nf][fm][e] = 0.0f;

    for (int kt = 0; kt < SEQ / 64; kt++) {
        __syncthreads();
        // ---- stage K from registers ----
        *(uint4*)&Kh[krow * FST + kc0]     = pkh0;
        *(uint4*)&Kh[krow * FST + kc0 + 4] = pkh1;
        *(uint4*)&Kl[krow * FST + kc0]     = pkl0;
        *(uint4*)&Kl[krow * FST + kc0 + 4] = pkl1;
        // ---- stage V^T from registers (pure copy) ----
        {
            int vb0 = vd * FST + vc * 8;
            *(uint2*)&Vt[vb0]     = make_uint2(pv0.x, pv0.y);
            *(uint2*)&Vt[vb0 + 2] = make_uint2(pv0.z, pv0.w);
            *(uint2*)&Vt[vb0 + 4] = make_uint2(pv1.x, pv1.y);
            *(uint2*)&Vt[vb0 + 6] = make_uint2(pv1.z, pv1.w);
        }
        __syncthreads();

        // ---- prefetch tile kt+1 (completes during compute) ----
        if (kt + 1 < SEQ / 64) {
            size_t gw = (rowbase + (kt + 1) * 64 + krow) * 512 + h * 32 + kc0;
            pkh0 = *(const uint4*)&khg[gw];
            pkh1 = *(const uint4*)&khg[gw + 4];
            pkl0 = *(const uint4*)&klg[gw];
            pkl1 = *(const uint4*)&klg[gw + 4];
            size_t vw = vrow + (kt + 1) * 32 + vc * 8;
            pv0 = *(const uint4*)&vtg[vw];
            pv1 = *(const uint4*)&vtg[vw + 4];
        }

        // ---- S^T = K·Q^T (bf16x3); K carries scale*log2e already ----
        floatx4 sacc[2][4];
        #pragma unroll
        for (int nf = 0; nf < 2; nf++)
            #pragma unroll
            for (int fm = 0; fm < 4; fm++)
                #pragma unroll
                for (int e = 0; e < 4; e++) sacc[nf][fm][e] = 0.0f;

        #pragma unroll
        for (int s = 0; s < 2; s++) {
            bf16x8 vqh[2], vql[2];
            #pragma unroll
            for (int nf = 0; nf < 2; nf++) {
                int qi = (w * 32 + nf * 16 + l15) * FST + s * 16 + quad * 4;
                vqh[nf] = *(const bf16x8*)&Qh[qi];
                vql[nf] = *(const bf16x8*)&Ql[qi];
            }
            #pragma unroll
            for (int fm = 0; fm < 4; fm++) {
                int ki = (fm * 16 + l15) * FST + s * 16 + quad * 4;
                bf16x8 vkh = *(const bf16x8*)&Kh[ki];
                bf16x8 vkl = *(const bf16x8*)&Kl[ki];
                #pragma unroll
                for (int nf = 0; nf < 2; nf++) {
                    sacc[nf][fm] = __builtin_amdgcn_mfma_f32_16x16x32_bf16(vkh, vqh[nf], sacc[nf][fm], 0, 0, 0);
                    sacc[nf][fm] = __builtin_amdgcn_mfma_f32_16x16x32_bf16(vkh, vql[nf], sacc[nf][fm], 0, 0, 0);
                    sacc[nf][fm] = __builtin_amdgcn_mfma_f32_16x16x32_bf16(vkl, vqh[nf], sacc[nf][fm], 0, 0, 0);
                }
            }
        }

        // ---- online softmax (base-2 domain, raw v_exp_f32) ----
        #pragma unroll
        for (int nf = 0; nf < 2; nf++) {
            float p[4][4];
            float mt = -INFINITY;
            #pragma unroll
            for (int fm = 0; fm < 4; fm++)
                #pragma unroll
                for (int r = 0; r < 4; r++) {
                    p[fm][r] = sacc[nf][fm][r];
                    mt = fmaxf(mt, p[fm][r]);
                }
            mt = fmaxf(mt, __shfl_xor(mt, 16));
            mt = fmaxf(mt, __shfl_xor(mt, 32));
            float m_new = fmaxf(m_i[nf], mt);
            float alpha = EXP2(m_i[nf] - m_new);
            float rs = 0.0f;
            #pragma unroll
            for (int fm = 0; fm < 4; fm++)
                #pragma unroll
                for (int r = 0; r < 4; r++) {
                    p[fm][r] = EXP2(p[fm][r] - m_new);
                    rs += p[fm][r];
                }
            rs += __shfl_xor(rs, 16);
            rs += __shfl_xor(rs, 32);
            l_i[nf] = l_i[nf] * alpha + rs;
            m_i[nf] = m_new;
            #pragma unroll
            for (int fm = 0; fm < 4; fm++)
                #pragma unroll
                for (int e = 0; e < 4; e++) acc_o[nf][fm][e] *= alpha;

            int qrow = w * 32 + nf * 16 + l15;
            #pragma unroll
            for (int fm = 0; fm < 4; fm++) {
                uint32_t u0 = pack_bf16_rne(p[fm][0], p[fm][1]);
                uint32_t u1 = pack_bf16_rne(p[fm][2], p[fm][3]);
                *(uint2*)&Pt[qrow * FST + fm * 8 + quad * 2] = make_uint2(u0, u1);
            }
        }

        // ---- O^T += Vt · P^T ----
        #pragma unroll
        for (int s = 0; s < 2; s++) {
            bf16x8 pb[2];
            #pragma unroll
            for (int nf = 0; nf < 2; nf++)
                pb[nf] = *(const bf16x8*)&Pt[(w * 32 + nf * 16 + l15) * FST + s * 16 + quad * 4];
            #pragma unroll
            for (int fm = 0; fm < 4; fm++) {
                bf16x8 va = *(const bf16x8*)&Vt[(fm * 16 + l15) * FST + s * 16 + quad * 4];
                #pragma unroll
                for (int nf = 0; nf < 2; nf++)
                    acc_o[nf][fm] = __builtin_amdgcn_mfma_f32_16x16x32_bf16(va, pb[nf], acc_o[nf][fm], 0, 0, 0);
            }
        }
    }

    // ---- epilogue: write x pre-split bf16 ----
    #pragma unroll
    for (int nf = 0; nf < 2; nf++) {
        float rl = 1.0f / l_i[nf];
        size_t row = rowbase + qb * 128 + w * 32 + nf * 16 + l15;
        #pragma unroll
        for (int fm = 0; fm < 4; fm++) {
            int d0 = fm * 16 + quad * 4;
            uint32_t h0, l0, h1, l1;
            split2(acc_o[nf][fm][0] * rl, acc_o[nf][fm][1] * rl, h0, l0);
            split2(acc_o[nf][fm][2] * rl, acc_o[nf][fm][3] * rl, h1, l1);
            size_t wi = row * 512 + ((h * 64 + d0) >> 1);
            *(uint2*)&xhg[wi] = make_uint2(h0, h1);
            *(uint2*)&xlg[wi] = make_uint2(l0, l1);
        }
    }
}

extern "C" void kernel_launch(void* const* d_in, const int* in_sizes, int n_in,
                              void* d_out, int out_size, void* d_ws, size_t ws_size,
                              hipStream_t stream)
{
    const float* input_qv = (const float*)d_in[0];
    const float* input_k  = (const float*)d_in[1];
    const float* W_qv     = (const float*)d_in[2];
    const float* W_k      = (const float*)d_in[3];
    const float* W_proj   = (const float*)d_in[4];
    const float* b_proj   = (const float*)d_in[5];
    float* out = (float*)d_out;

    const size_t RW = 4096 * 512;            // words per [4096][1024-bf16] buffer
    uint32_t* qh = (uint32_t*)d_ws;          // 5 RW = 41.9 MB total
    uint32_t* ql = qh + RW;
    uint32_t* vt = ql + RW;                  // V^T [16 h][64 d][4096 tok] bf16 = 1 RW
    uint32_t* xh = vt + RW;
    uint32_t* xl = xh + RW;
    uint32_t* kh = (uint32_t*)d_out;         // split K parked in d_out (16.8 MB);
    uint32_t* kl = kh + RW;                  // proj GEMM rewrites out afterwards

    dim3 blk(256);
    // fused qv+k projections: 768 blocks = exactly 3/CU
    gemm_qvk<<<dim3(24, 32), blk, 0, stream>>>(
        input_qv, input_k, W_qv, W_k, qh, ql, (ushort*)vt, kh, kl);
    // flash attention (register prefetch; V pre-transposed; raw v_exp_f32)
    flash_attn<<<dim3(SEQ / 128, NH, BATCH), blk, 0, stream>>>(
        qh, ql, kh, kl, vt, xh, xl);
    // output projection + bias
    gemm_proj<<<dim3(16, 32), blk, 0, stream>>>(
        xh, xl, W_proj, b_proj, out);
}